// Round 4
// baseline (678.092 us; speedup 1.0000x reference)
//
#include <hip/hip_runtime.h>

#define N_NODES 50000
#define N_EDGES 800000
#define N_GRAPH 1000

typedef short bf16x8 __attribute__((ext_vector_type(8)));
typedef float f32x4 __attribute__((ext_vector_type(4)));

__device__ inline short f2b(float f) {   // f32 -> bf16 (RNE)
    union { float f; unsigned u; } x; x.f = f;
    unsigned r = x.u + 0x7FFF + ((x.u >> 16) & 1);
    return (short)(r >> 16);
}
__device__ inline float b2f_lo(unsigned v) {   // low bf16 of a packed uint -> f32
    union { unsigned u; float f; } x; x.u = v << 16; return x.f;
}
__device__ inline float b2f_hi(unsigned v) {   // high bf16 -> f32
    union { unsigned u; float f; } x; x.u = v & 0xFFFF0000u; return x.f;
}
__device__ inline float b2f_s(short s) {
    union { unsigned u; float f; } x; x.u = ((unsigned)(unsigned short)s) << 16; return x.f;
}

// ---------------- layer GEMM: A[N,128] @ W[128,128] -> out f32 + bf16 copy ----------------
__global__ __launch_bounds__(256) void gemm128(const float* __restrict__ A,
                                               const float* __restrict__ W,
                                               float* __restrict__ out,
                                               short* __restrict__ outb, int nrows) {
    __shared__ float sA[16][68];
    __shared__ float sB[16][132];
    const int tid = threadIdx.x;
    const int tx = tid & 15, ty = tid >> 4;
    const int n0 = blockIdx.x * 64;
    float acc[4][8];
#pragma unroll
    for (int i = 0; i < 4; i++)
#pragma unroll
        for (int j = 0; j < 8; j++) acc[i][j] = 0.f;

    const int lrow = tid >> 2;
    const int lq   = tid & 3;

    for (int k0 = 0; k0 < 128; k0 += 16) {
        __syncthreads();
        float4 av = make_float4(0.f, 0.f, 0.f, 0.f);
        int gr = n0 + lrow;
        if (gr < nrows) av = *(const float4*)(A + (size_t)gr * 128 + k0 + lq * 4);
        sA[lq * 4 + 0][lrow] = av.x;
        sA[lq * 4 + 1][lrow] = av.y;
        sA[lq * 4 + 2][lrow] = av.z;
        sA[lq * 4 + 3][lrow] = av.w;
        {
            int krow = tid >> 4;
            int bc = (tid & 15) * 8;
            const float* wp = W + (size_t)(k0 + krow) * 128 + bc;
            *(float4*)&sB[krow][bc]     = *(const float4*)(wp);
            *(float4*)&sB[krow][bc + 4] = *(const float4*)(wp + 4);
        }
        __syncthreads();
#pragma unroll
        for (int kk = 0; kk < 16; kk++) {
            float a[4], b[8];
#pragma unroll
            for (int i = 0; i < 4; i++) a[i] = sA[kk][ty * 4 + i];
#pragma unroll
            for (int j = 0; j < 8; j++) b[j] = sB[kk][tx * 8 + j];
#pragma unroll
            for (int i = 0; i < 4; i++)
#pragma unroll
                for (int j = 0; j < 8; j++) acc[i][j] += a[i] * b[j];
        }
    }
#pragma unroll
    for (int i = 0; i < 4; i++) {
        int gr = n0 + ty * 4 + i;
        if (gr < nrows) {
            float* op = out + (size_t)gr * 128 + tx * 8;
            *(float4*)(op)     = make_float4(acc[i][0], acc[i][1], acc[i][2], acc[i][3]);
            *(float4*)(op + 4) = make_float4(acc[i][4], acc[i][5], acc[i][6], acc[i][7]);
            short* bp = outb + (size_t)gr * 128 + tx * 8;
            *(short4*)(bp)     = make_short4(f2b(acc[i][0]), f2b(acc[i][1]),
                                             f2b(acc[i][2]), f2b(acc[i][3]));
            *(short4*)(bp + 4) = make_short4(f2b(acc[i][4]), f2b(acc[i][5]),
                                             f2b(acc[i][6]), f2b(acc[i][7]));
        }
    }
}

// ---------------- per-node attention coefficients ----------------
__global__ void node_al(const float* __restrict__ xs, const float* __restrict__ a_s,
                        const float* __restrict__ a_d, float* __restrict__ alsrc,
                        float* __restrict__ aldst, int n) {
    int t = blockIdx.x * blockDim.x + threadIdx.x;
    if (t >= n * 8) return;
    int node = t >> 3, h = t & 7;
    const float4* xp = (const float4*)(xs + (size_t)node * 128 + h * 16);
    const float4* sp = (const float4*)(a_s + h * 16);
    const float4* dp = (const float4*)(a_d + h * 16);
    float ss = 0.f, dd = 0.f;
#pragma unroll
    for (int q = 0; q < 4; q++) {
        float4 x4 = xp[q], s4 = sp[q], d4 = dp[q];
        ss += x4.x * s4.x + x4.y * s4.y + x4.z * s4.z + x4.w * s4.w;
        dd += x4.x * d4.x + x4.y * d4.y + x4.z * d4.z + x4.w * d4.w;
    }
    alsrc[t] = ss;
    aldst[t] = dd;
}

// ---------------- aeW[k][h] = sum_c We[k, h*16+c] * ae[h,c] ----------------
__global__ void aew_k(const float* __restrict__ We, const float* __restrict__ ae,
                      float* __restrict__ aeW) {
    int t = threadIdx.x;   // 128 threads
    int k = t >> 3, h = t & 7;
    float s = 0.f;
#pragma unroll
    for (int c = 0; c < 16; c++) s += We[k * 128 + h * 16 + c] * ae[h * 16 + c];
    aeW[k * 8 + h] = s;
}

// ---------------- CSR build ----------------
__global__ void hist_k(const int* __restrict__ ei, int* __restrict__ cnt, int ne) {
    int e = blockIdx.x * blockDim.x + threadIdx.x;
    if (e < ne) atomicAdd(&cnt[ei[ne + e]], 1);
}

__global__ void scan1_k(const int* __restrict__ cnt, int* __restrict__ rowptr,
                        int* __restrict__ part, int n) {
    __shared__ int s[256];
    int tid = threadIdx.x;
    int i = blockIdx.x * 256 + tid;
    int v = (i < n) ? cnt[i] : 0;
    s[tid] = v; __syncthreads();
#pragma unroll
    for (int off = 1; off < 256; off <<= 1) {
        int t = (tid >= off) ? s[tid - off] : 0;
        __syncthreads();
        s[tid] += t;
        __syncthreads();
    }
    if (i < n) rowptr[i] = s[tid] - v;
    if (tid == 255) part[blockIdx.x] = s[255];
}

__global__ void scan2_k(int* __restrict__ part, int npart) {
    __shared__ int s[256];
    int tid = threadIdx.x;
    int v = (tid < npart) ? part[tid] : 0;
    s[tid] = v; __syncthreads();
#pragma unroll
    for (int off = 1; off < 256; off <<= 1) {
        int t = (tid >= off) ? s[tid - off] : 0;
        __syncthreads();
        s[tid] += t;
        __syncthreads();
    }
    if (tid < npart) part[tid] = s[tid] - v;
}

__global__ void scan3_k(int* __restrict__ rowptr, const int* __restrict__ part,
                        int* __restrict__ cursor, int n, int ne) {
    int i = blockIdx.x * 256 + threadIdx.x;
    if (i < n) {
        int r = rowptr[i] + part[blockIdx.x];
        rowptr[i] = r;
        cursor[i] = r;
    }
    if (i == 0) rowptr[n] = ne;
}

__global__ void scatter_k(const int* __restrict__ ei, int* __restrict__ cursor,
                          int* __restrict__ pos, int* __restrict__ csr_src, int ne) {
    int e = blockIdx.x * blockDim.x + threadIdx.x;
    if (e >= ne) return;
    int d = ei[ne + e];
    int p = atomicAdd(&cursor[d], 1);
    pos[e] = p;
    csr_src[p] = ei[e];
}

// ---------------- per-edge logits (alsrc + al_e), bf16, CSR order ----------------
__global__ __launch_bounds__(256) void ale_k(const int* __restrict__ ei,
                                             const float* __restrict__ eattr,
                                             const float* __restrict__ alsrc,
                                             const float* __restrict__ aeW,
                                             const int* __restrict__ pos,
                                             short* __restrict__ aleb, int ne) {
    __shared__ float sAe[128];
    if (threadIdx.x < 128) sAe[threadIdx.x] = aeW[threadIdx.x];
    __syncthreads();
    int e = blockIdx.x * blockDim.x + threadIdx.x;
    if (e >= ne) return;
    float ea[16];
    const float4* ep = (const float4*)(eattr + (size_t)e * 16);
#pragma unroll
    for (int q = 0; q < 4; q++) {
        float4 v = ep[q];
        ea[q * 4 + 0] = v.x; ea[q * 4 + 1] = v.y; ea[q * 4 + 2] = v.z; ea[q * 4 + 3] = v.w;
    }
    int s = ei[e];
    float out[8];
#pragma unroll
    for (int h = 0; h < 8; h++) out[h] = alsrc[s * 8 + h];
#pragma unroll
    for (int k = 0; k < 16; k++)
#pragma unroll
        for (int h = 0; h < 8; h++) out[h] += ea[k] * sAe[k * 8 + h];
    short v8[8];
#pragma unroll
    for (int h = 0; h < 8; h++) v8[h] = f2b(out[h]);
    short* op = aleb + (size_t)pos[e] * 8;
    *(short4*)(op)     = make_short4(v8[0], v8[1], v8[2], v8[3]);
    *(short4*)(op + 4) = make_short4(v8[4], v8[5], v8[6], v8[7]);
}

// ---------------- gather: one wave per dst; bf16 xs rows; fused normalize+bias ----------------
// lane owns channels 2*lane and 2*lane+1 (both in head lane>>3)
__global__ __launch_bounds__(256) void gather_k(const int* __restrict__ rowptr,
                                                const int* __restrict__ csr_src,
                                                const short* __restrict__ aleb,
                                                const float* __restrict__ aldst,
                                                const short* __restrict__ xsb,
                                                const float* __restrict__ b,
                                                float* __restrict__ hout, int n) {
    int dst = blockIdx.x * 4 + (threadIdx.x >> 6);
    if (dst >= n) return;
    int lane = threadIdx.x & 63;
    int p0 = rowptr[dst], p1 = rowptr[dst + 1];
    float ald = aldst[dst * 8 + (lane & 7)];
    float den = 0.f, acc0 = 0.f, acc1 = 0.f;
    for (int p = p0; p < p1; ++p) {
        int s = csr_src[p];
        float al = (lane < 8) ? b2f_s(aleb[(size_t)p * 8 + lane]) : 0.f;
        float lg = al + ald;
        lg = lg > 0.f ? lg : 0.2f * lg;        // leaky_relu(0.2)
        float ex = expf(lg);
        den += ex;                              // lanes 0..7 authoritative
        float exh = __shfl(ex, lane >> 3);      // head of channels 2*lane, 2*lane+1
        unsigned v = *(const unsigned*)(xsb + (size_t)s * 128 + lane * 2);
        acc0 += b2f_lo(v) * exh;
        acc1 += b2f_hi(v) * exh;
    }
    float d = __shfl(den, lane >> 3);
    float inv = 1.f / (d + 1e-16f);
    const float2 bb = *(const float2*)(b + lane * 2);
    float2 o = make_float2(acc0 * inv + bb.x, acc1 * inv + bb.y);
    *(float2*)(hout + (size_t)dst * 128 + lane * 2) = o;
}

// ---------------- global add pool ----------------
__global__ void pool_k(const float* __restrict__ h3, const int* __restrict__ batch,
                       float* __restrict__ pool, int n) {
    int t = blockIdx.x * blockDim.x + threadIdx.x;
    if (t >= n * 128) return;
    int node = t >> 7, j = t & 127;
    atomicAdd(pool + (size_t)batch[node] * 128 + j, h3[t]);
}

// ---------------- Wl1 [512(k),512(c)] f32 -> Wl1T [c][k] bf16 ----------------
__global__ void wl1t_k(const float* __restrict__ Wl1, short* __restrict__ Wl1T) {
    int idx = blockIdx.x * blockDim.x + threadIdx.x;   // 262144
    int k = idx >> 9, c = idx & 511;
    Wl1T[(size_t)c * 512 + k] = f2b(Wl1[idx]);
}

__global__ void init_out(float* __restrict__ out, const float* __restrict__ bl2, int n) {
    int t = blockIdx.x * blockDim.x + threadIdx.x;
    if (t < n) out[t] = bl2[0];
}

// ---------------- fused final MLP via bf16 MFMA ----------------
__global__ __launch_bounds__(256) void final_mfma(
    const float* __restrict__ h1, const float* __restrict__ h2,
    const float* __restrict__ h3, const float* __restrict__ pool,
    const int* __restrict__ batch, const short* __restrict__ Wl1T,
    const float* __restrict__ bl1, const float* __restrict__ Wl2,
    float* __restrict__ out, int nrows)
{
    __shared__ short Abuf[64 * 40];
    __shared__ short Bbuf[256 * 40];
    __shared__ int   sBatch[64];
    const int tid = threadIdx.x;
    const int n0 = blockIdx.x * 64;
    const int j0 = blockIdx.y * 256;
    const int wid = tid >> 6, lane = tid & 63;
    const int lr = lane & 15, kg = lane >> 4;

    if (tid < 64) {
        int gr = n0 + tid;
        sBatch[tid] = (gr < nrows) ? batch[gr] : 0;
    }
    float w2[4], b1c[4];
#pragma unroll
    for (int fn = 0; fn < 4; fn++) {
        int c = j0 + wid * 64 + fn * 16 + lr;
        w2[fn]  = Wl2[c];
        b1c[fn] = bl1[c];
    }

    f32x4 acc[4][4] = {};

    for (int k0 = 0; k0 < 512; k0 += 32) {
        const int seg = k0 >> 7;
        const float* base = (seg == 0) ? h1 : (seg == 1) ? h2 : (seg == 2) ? h3 : pool;
        const int cseg = k0 & 127;
        __syncthreads();
#pragma unroll
        for (int i = 0; i < 2; i++) {
            int idx = tid + i * 256;
            int row = idx >> 3;
            int slot = idx & 7;
            float4 v = make_float4(0.f, 0.f, 0.f, 0.f);
            int gr = n0 + row;
            if (gr < nrows) {
                int grow = (seg == 3) ? sBatch[row] : gr;
                v = *(const float4*)(base + (size_t)grow * 128 + cseg + slot * 4);
            }
            *(short4*)(&Abuf[row * 40 + slot * 4]) =
                make_short4(f2b(v.x), f2b(v.y), f2b(v.z), f2b(v.w));
        }
#pragma unroll
        for (int i = 0; i < 4; i++) {
            int idx = tid + i * 256;
            int c = idx >> 2, slot = idx & 3;
            uint4 v = *(const uint4*)(Wl1T + (size_t)(j0 + c) * 512 + k0 + slot * 8);
            *(uint4*)(&Bbuf[c * 40 + slot * 8]) = v;
        }
        __syncthreads();
        bf16x8 a[4], b[4];
#pragma unroll
        for (int fm = 0; fm < 4; fm++)
            a[fm] = *(const bf16x8*)(&Abuf[(fm * 16 + lr) * 40 + kg * 8]);
#pragma unroll
        for (int fn = 0; fn < 4; fn++)
            b[fn] = *(const bf16x8*)(&Bbuf[(wid * 64 + fn * 16 + lr) * 40 + kg * 8]);
#pragma unroll
        for (int fm = 0; fm < 4; fm++)
#pragma unroll
            for (int fn = 0; fn < 4; fn++)
                acc[fm][fn] = __builtin_amdgcn_mfma_f32_16x16x32_bf16(
                    a[fm], b[fn], acc[fm][fn], 0, 0, 0);
    }

#pragma unroll
    for (int fm = 0; fm < 4; fm++) {
#pragma unroll
        for (int r = 0; r < 4; r++) {
            float s = 0.f;
#pragma unroll
            for (int fn = 0; fn < 4; fn++) {
                float z = acc[fm][fn][r] + b1c[fn];
                z = z > 0.f ? z : 0.01f * z;
                s += z * w2[fn];
            }
            s += __shfl_xor(s, 1);
            s += __shfl_xor(s, 2);
            s += __shfl_xor(s, 4);
            s += __shfl_xor(s, 8);
            if (lr == 0) {
                int gr = n0 + fm * 16 + kg * 4 + r;
                if (gr < nrows) atomicAdd(out + gr, s);
            }
        }
    }
}

extern "C" void kernel_launch(void* const* d_in, const int* in_sizes, int n_in,
                              void* d_out, int out_size, void* d_ws, size_t ws_size,
                              hipStream_t stream) {
    const float* x     = (const float*)d_in[0];
    const int*   ei    = (const int*)d_in[1];
    const float* eattr = (const float*)d_in[2];
    const int*   batch = (const int*)d_in[3];
    const float* W[3]   = {(const float*)d_in[4],  (const float*)d_in[10], (const float*)d_in[16]};
    const float* We[3]  = {(const float*)d_in[5],  (const float*)d_in[11], (const float*)d_in[17]};
    const float* as_[3] = {(const float*)d_in[6],  (const float*)d_in[12], (const float*)d_in[18]};
    const float* ad_[3] = {(const float*)d_in[7],  (const float*)d_in[13], (const float*)d_in[19]};
    const float* ae_[3] = {(const float*)d_in[8],  (const float*)d_in[14], (const float*)d_in[20]};
    const float* b_[3]  = {(const float*)d_in[9],  (const float*)d_in[15], (const float*)d_in[21]};
    const float* Wl1 = (const float*)d_in[22];
    const float* bl1 = (const float*)d_in[23];
    const float* Wl2 = (const float*)d_in[24];
    const float* bl2 = (const float*)d_in[25];

    const int N = N_NODES, E = N_EDGES, G = N_GRAPH;

    float* ws    = (float*)d_ws;
    float* xs    = ws;                          // N*128 f32
    float* h0    = xs + (size_t)N * 128;
    float* h1b   = h0 + (size_t)N * 128;
    float* h2b   = h1b + (size_t)N * 128;
    float* hbuf[3] = {h0, h1b, h2b};
    float* alsrc = h2b + (size_t)N * 128;       // N*8
    float* aldst = alsrc + (size_t)N * 8;       // N*8
    float* pool  = aldst + (size_t)N * 8;       // G*128
    float* aeW   = pool + (size_t)G * 128;      // 128
    short* xsb   = (short*)(aeW + 128);         // N*128 bf16
    short* aleb  = xsb + (size_t)N * 128;       // E*8 bf16
    short* wl1t  = aleb + (size_t)E * 8;        // 512*512 bf16
    int*   cnt     = (int*)(wl1t + 512 * 512);  // N
    int*   rowptr  = cnt + N;                   // N+1
    int*   cursor  = rowptr + N + 1;            // N
    int*   part    = cursor + N;                // 256
    int*   pos     = part + 256;                // E
    int*   csr_src = pos + E;                   // E

    // ---- once per call: transpose Wl1, build dst-CSR ----
    wl1t_k<<<1024, 256, 0, stream>>>(Wl1, wl1t);
    hipMemsetAsync(cnt, 0, (size_t)N * sizeof(int), stream);
    hist_k<<<(E + 255) / 256, 256, 0, stream>>>(ei, cnt, E);
    const int nblk = (N + 255) / 256;   // 196
    scan1_k<<<nblk, 256, 0, stream>>>(cnt, rowptr, part, N);
    scan2_k<<<1, 256, 0, stream>>>(part, nblk);
    scan3_k<<<nblk, 256, 0, stream>>>(rowptr, part, cursor, N, E);
    scatter_k<<<(E + 255) / 256, 256, 0, stream>>>(ei, cursor, pos, csr_src, E);

    for (int l = 0; l < 3; l++) {
        const float* Ain = (l == 0) ? x : hbuf[l - 1];
        gemm128<<<(N + 63) / 64, 256, 0, stream>>>(Ain, W[l], xs, xsb, N);
        node_al<<<(N * 8 + 255) / 256, 256, 0, stream>>>(xs, as_[l], ad_[l], alsrc, aldst, N);
        aew_k<<<1, 128, 0, stream>>>(We[l], ae_[l], aeW);
        ale_k<<<(E + 255) / 256, 256, 0, stream>>>(ei, eattr, alsrc, aeW, pos, aleb, E);
        gather_k<<<(N + 3) / 4, 256, 0, stream>>>(rowptr, csr_src, aleb, aldst, xsb,
                                                  b_[l], hbuf[l], N);
    }
    hipMemsetAsync(pool, 0, (size_t)G * 128 * sizeof(float), stream);
    pool_k<<<(N * 128 + 255) / 256, 256, 0, stream>>>(hbuf[2], batch, pool, N);

    init_out<<<(N + 255) / 256, 256, 0, stream>>>((float*)d_out, bl2, N);
    dim3 fg((N + 63) / 64, 2);
    final_mfma<<<fg, 256, 0, stream>>>(hbuf[0], hbuf[1], hbuf[2], pool, batch,
                                       wl1t, bl1, Wl2, (float*)d_out, N);
}

// Round 5
// 574.174 us; speedup vs baseline: 1.1810x; 1.1810x over previous
//
#include <hip/hip_runtime.h>

#define N_NODES 50000
#define N_EDGES 800000
#define N_GRAPH 1000

typedef short bf16x8 __attribute__((ext_vector_type(8)));
typedef float f32x4 __attribute__((ext_vector_type(4)));

__device__ inline short f2b(float f) {   // f32 -> bf16 (RNE)
    union { float f; unsigned u; } x; x.f = f;
    unsigned r = x.u + 0x7FFF + ((x.u >> 16) & 1);
    return (short)(r >> 16);
}
__device__ inline float b2f_lo(unsigned v) {   // low bf16 of a packed uint -> f32
    union { unsigned u; float f; } x; x.u = v << 16; return x.f;
}
__device__ inline float b2f_hi(unsigned v) {   // high bf16 -> f32
    union { unsigned u; float f; } x; x.u = v & 0xFFFF0000u; return x.f;
}
__device__ inline float b2f_s(short s) {
    union { unsigned u; float f; } x; x.u = ((unsigned)(unsigned short)s) << 16; return x.f;
}

// ---------------- layer GEMM: A[N,128] @ W[128,128] -> out f32 + bf16 copy ----------------
__global__ __launch_bounds__(256) void gemm128(const float* __restrict__ A,
                                               const float* __restrict__ W,
                                               float* __restrict__ out,
                                               short* __restrict__ outb, int nrows) {
    __shared__ float sA[16][68];
    __shared__ float sB[16][132];
    const int tid = threadIdx.x;
    const int tx = tid & 15, ty = tid >> 4;
    const int n0 = blockIdx.x * 64;
    float acc[4][8];
#pragma unroll
    for (int i = 0; i < 4; i++)
#pragma unroll
        for (int j = 0; j < 8; j++) acc[i][j] = 0.f;

    const int lrow = tid >> 2;
    const int lq   = tid & 3;

    for (int k0 = 0; k0 < 128; k0 += 16) {
        __syncthreads();
        float4 av = make_float4(0.f, 0.f, 0.f, 0.f);
        int gr = n0 + lrow;
        if (gr < nrows) av = *(const float4*)(A + (size_t)gr * 128 + k0 + lq * 4);
        sA[lq * 4 + 0][lrow] = av.x;
        sA[lq * 4 + 1][lrow] = av.y;
        sA[lq * 4 + 2][lrow] = av.z;
        sA[lq * 4 + 3][lrow] = av.w;
        {
            int krow = tid >> 4;
            int bc = (tid & 15) * 8;
            const float* wp = W + (size_t)(k0 + krow) * 128 + bc;
            *(float4*)&sB[krow][bc]     = *(const float4*)(wp);
            *(float4*)&sB[krow][bc + 4] = *(const float4*)(wp + 4);
        }
        __syncthreads();
#pragma unroll
        for (int kk = 0; kk < 16; kk++) {
            float a[4], b[8];
#pragma unroll
            for (int i = 0; i < 4; i++) a[i] = sA[kk][ty * 4 + i];
#pragma unroll
            for (int j = 0; j < 8; j++) b[j] = sB[kk][tx * 8 + j];
#pragma unroll
            for (int i = 0; i < 4; i++)
#pragma unroll
                for (int j = 0; j < 8; j++) acc[i][j] += a[i] * b[j];
        }
    }
#pragma unroll
    for (int i = 0; i < 4; i++) {
        int gr = n0 + ty * 4 + i;
        if (gr < nrows) {
            float* op = out + (size_t)gr * 128 + tx * 8;
            *(float4*)(op)     = make_float4(acc[i][0], acc[i][1], acc[i][2], acc[i][3]);
            *(float4*)(op + 4) = make_float4(acc[i][4], acc[i][5], acc[i][6], acc[i][7]);
            short* bp = outb + (size_t)gr * 128 + tx * 8;
            *(short4*)(bp)     = make_short4(f2b(acc[i][0]), f2b(acc[i][1]),
                                             f2b(acc[i][2]), f2b(acc[i][3]));
            *(short4*)(bp + 4) = make_short4(f2b(acc[i][4]), f2b(acc[i][5]),
                                             f2b(acc[i][6]), f2b(acc[i][7]));
        }
    }
}

// ---------------- per-node attention coefficients ----------------
__global__ void node_al(const float* __restrict__ xs, const float* __restrict__ a_s,
                        const float* __restrict__ a_d, float* __restrict__ alsrc,
                        float* __restrict__ aldst, int n) {
    int t = blockIdx.x * blockDim.x + threadIdx.x;
    if (t >= n * 8) return;
    int node = t >> 3, h = t & 7;
    const float4* xp = (const float4*)(xs + (size_t)node * 128 + h * 16);
    const float4* sp = (const float4*)(a_s + h * 16);
    const float4* dp = (const float4*)(a_d + h * 16);
    float ss = 0.f, dd = 0.f;
#pragma unroll
    for (int q = 0; q < 4; q++) {
        float4 x4 = xp[q], s4 = sp[q], d4 = dp[q];
        ss += x4.x * s4.x + x4.y * s4.y + x4.z * s4.z + x4.w * s4.w;
        dd += x4.x * d4.x + x4.y * d4.y + x4.z * d4.z + x4.w * d4.w;
    }
    alsrc[t] = ss;
    aldst[t] = dd;
}

// ---------------- aeW[k][h] = sum_c We[k, h*16+c] * ae[h,c] ----------------
__global__ void aew_k(const float* __restrict__ We, const float* __restrict__ ae,
                      float* __restrict__ aeW) {
    int t = threadIdx.x;   // 128 threads
    int k = t >> 3, h = t & 7;
    float s = 0.f;
#pragma unroll
    for (int c = 0; c < 16; c++) s += We[k * 128 + h * 16 + c] * ae[h * 16 + c];
    aeW[k * 8 + h] = s;
}

// ---------------- CSR build ----------------
__global__ void hist_k(const int* __restrict__ ei, int* __restrict__ cnt, int ne) {
    int e = blockIdx.x * blockDim.x + threadIdx.x;
    if (e < ne) atomicAdd(&cnt[ei[ne + e]], 1);
}

__global__ void scan1_k(const int* __restrict__ cnt, int* __restrict__ rowptr,
                        int* __restrict__ part, int n) {
    __shared__ int s[256];
    int tid = threadIdx.x;
    int i = blockIdx.x * 256 + tid;
    int v = (i < n) ? cnt[i] : 0;
    s[tid] = v; __syncthreads();
#pragma unroll
    for (int off = 1; off < 256; off <<= 1) {
        int t = (tid >= off) ? s[tid - off] : 0;
        __syncthreads();
        s[tid] += t;
        __syncthreads();
    }
    if (i < n) rowptr[i] = s[tid] - v;
    if (tid == 255) part[blockIdx.x] = s[255];
}

__global__ void scan2_k(int* __restrict__ part, int npart) {
    __shared__ int s[256];
    int tid = threadIdx.x;
    int v = (tid < npart) ? part[tid] : 0;
    s[tid] = v; __syncthreads();
#pragma unroll
    for (int off = 1; off < 256; off <<= 1) {
        int t = (tid >= off) ? s[tid - off] : 0;
        __syncthreads();
        s[tid] += t;
        __syncthreads();
    }
    if (tid < npart) part[tid] = s[tid] - v;
}

__global__ void scan3_k(int* __restrict__ rowptr, const int* __restrict__ part,
                        int* __restrict__ cursor, int n, int ne) {
    int i = blockIdx.x * 256 + threadIdx.x;
    if (i < n) {
        int r = rowptr[i] + part[blockIdx.x];
        rowptr[i] = r;
        cursor[i] = r;
    }
    if (i == 0) rowptr[n] = ne;
}

__global__ void scatter_k(const int* __restrict__ ei, int* __restrict__ cursor,
                          int* __restrict__ pos, int* __restrict__ csr_src, int ne) {
    int e = blockIdx.x * blockDim.x + threadIdx.x;
    if (e >= ne) return;
    int d = ei[ne + e];
    int p = atomicAdd(&cursor[d], 1);
    pos[e] = p;
    csr_src[p] = ei[e];
}

// ---------------- per-edge logits (alsrc + al_e), bf16, CSR order ----------------
__global__ __launch_bounds__(256) void ale_k(const int* __restrict__ ei,
                                             const float* __restrict__ eattr,
                                             const float* __restrict__ alsrc,
                                             const float* __restrict__ aeW,
                                             const int* __restrict__ pos,
                                             short* __restrict__ aleb, int ne) {
    __shared__ float sAe[128];
    if (threadIdx.x < 128) sAe[threadIdx.x] = aeW[threadIdx.x];
    __syncthreads();
    int e = blockIdx.x * blockDim.x + threadIdx.x;
    if (e >= ne) return;
    float ea[16];
    const float4* ep = (const float4*)(eattr + (size_t)e * 16);
#pragma unroll
    for (int q = 0; q < 4; q++) {
        float4 v = ep[q];
        ea[q * 4 + 0] = v.x; ea[q * 4 + 1] = v.y; ea[q * 4 + 2] = v.z; ea[q * 4 + 3] = v.w;
    }
    int s = ei[e];
    float out[8];
#pragma unroll
    for (int h = 0; h < 8; h++) out[h] = alsrc[s * 8 + h];
#pragma unroll
    for (int k = 0; k < 16; k++)
#pragma unroll
        for (int h = 0; h < 8; h++) out[h] += ea[k] * sAe[k * 8 + h];
    short v8[8];
#pragma unroll
    for (int h = 0; h < 8; h++) v8[h] = f2b(out[h]);
    short* op = aleb + (size_t)pos[e] * 8;
    *(short4*)(op)     = make_short4(v8[0], v8[1], v8[2], v8[3]);
    *(short4*)(op + 4) = make_short4(v8[4], v8[5], v8[6], v8[7]);
}

// ---------------- gather: one wave per dst; shuffle-free, native exp, 2x unroll ----------------
// lane owns channels 2*lane, 2*lane+1 (head lane>>3); every lane tracks its head's denom
__global__ __launch_bounds__(256) void gather_k(const int* __restrict__ rowptr,
                                                const int* __restrict__ csr_src,
                                                const short* __restrict__ aleb,
                                                const float* __restrict__ aldst,
                                                const short* __restrict__ xsb,
                                                const float* __restrict__ b,
                                                float* __restrict__ hout, int n) {
    int dst = blockIdx.x * 4 + (threadIdx.x >> 6);
    if (dst >= n) return;
    const int lane = threadIdx.x & 63;
    const int h = lane >> 3;
    const float L2E = 1.44269504f;
    int p0 = rowptr[dst], p1 = rowptr[dst + 1];
    float ald = aldst[dst * 8 + h];
    float den = 0.f, acc0 = 0.f, acc1 = 0.f;
    int p = p0;
    for (; p + 1 < p1; p += 2) {
        int s0 = csr_src[p];
        int s1 = csr_src[p + 1];
        float al0 = b2f_s(aleb[(size_t)p * 8 + h]);
        float al1 = b2f_s(aleb[(size_t)(p + 1) * 8 + h]);
        unsigned v0 = *(const unsigned*)(xsb + (size_t)s0 * 128 + lane * 2);
        unsigned v1 = *(const unsigned*)(xsb + (size_t)s1 * 128 + lane * 2);
        float lg0 = al0 + ald; lg0 = lg0 > 0.f ? lg0 : 0.2f * lg0;
        float lg1 = al1 + ald; lg1 = lg1 > 0.f ? lg1 : 0.2f * lg1;
        float ex0 = exp2f(lg0 * L2E);
        float ex1 = exp2f(lg1 * L2E);
        den  += ex0 + ex1;
        acc0 += b2f_lo(v0) * ex0 + b2f_lo(v1) * ex1;
        acc1 += b2f_hi(v0) * ex0 + b2f_hi(v1) * ex1;
    }
    if (p < p1) {
        int s0 = csr_src[p];
        float al0 = b2f_s(aleb[(size_t)p * 8 + h]);
        unsigned v0 = *(const unsigned*)(xsb + (size_t)s0 * 128 + lane * 2);
        float lg0 = al0 + ald; lg0 = lg0 > 0.f ? lg0 : 0.2f * lg0;
        float ex0 = exp2f(lg0 * L2E);
        den  += ex0;
        acc0 += b2f_lo(v0) * ex0;
        acc1 += b2f_hi(v0) * ex0;
    }
    float inv = 1.f / (den + 1e-16f);
    const float2 bb = *(const float2*)(b + lane * 2);
    float2 o = make_float2(acc0 * inv + bb.x, acc1 * inv + bb.y);
    *(float2*)(hout + (size_t)dst * 128 + lane * 2) = o;
}

// ---------------- global add pool ----------------
__global__ void pool_k(const float* __restrict__ h3, const int* __restrict__ batch,
                       float* __restrict__ pool, int n) {
    int t = blockIdx.x * blockDim.x + threadIdx.x;
    if (t >= n * 128) return;
    int node = t >> 7, j = t & 127;
    atomicAdd(pool + (size_t)batch[node] * 128 + j, h3[t]);
}

// ---------------- Wl1 [512(k),512(c)] f32 -> Wl1T [c][k] bf16 ----------------
__global__ void wl1t_k(const float* __restrict__ Wl1, short* __restrict__ Wl1T) {
    int idx = blockIdx.x * blockDim.x + threadIdx.x;   // 262144
    int k = idx >> 9, c = idx & 511;
    Wl1T[(size_t)c * 512 + k] = f2b(Wl1[idx]);
}

__global__ void init_out(float* __restrict__ out, const float* __restrict__ bl2, int n) {
    int t = blockIdx.x * blockDim.x + threadIdx.x;
    if (t < n) out[t] = bl2[0];
}

// ---------------- fused final MLP via bf16 MFMA ----------------
__global__ __launch_bounds__(256) void final_mfma(
    const float* __restrict__ h1, const float* __restrict__ h2,
    const float* __restrict__ h3, const float* __restrict__ pool,
    const int* __restrict__ batch, const short* __restrict__ Wl1T,
    const float* __restrict__ bl1, const float* __restrict__ Wl2,
    float* __restrict__ out, int nrows)
{
    __shared__ short Abuf[64 * 40];
    __shared__ short Bbuf[256 * 40];
    __shared__ int   sBatch[64];
    const int tid = threadIdx.x;
    const int n0 = blockIdx.x * 64;
    const int j0 = blockIdx.y * 256;
    const int wid = tid >> 6, lane = tid & 63;
    const int lr = lane & 15, kg = lane >> 4;

    if (tid < 64) {
        int gr = n0 + tid;
        sBatch[tid] = (gr < nrows) ? batch[gr] : 0;
    }
    float w2[4], b1c[4];
#pragma unroll
    for (int fn = 0; fn < 4; fn++) {
        int c = j0 + wid * 64 + fn * 16 + lr;
        w2[fn]  = Wl2[c];
        b1c[fn] = bl1[c];
    }

    f32x4 acc[4][4] = {};

    for (int k0 = 0; k0 < 512; k0 += 32) {
        const int seg = k0 >> 7;
        const float* base = (seg == 0) ? h1 : (seg == 1) ? h2 : (seg == 2) ? h3 : pool;
        const int cseg = k0 & 127;
        __syncthreads();
#pragma unroll
        for (int i = 0; i < 2; i++) {
            int idx = tid + i * 256;
            int row = idx >> 3;
            int slot = idx & 7;
            float4 v = make_float4(0.f, 0.f, 0.f, 0.f);
            int gr = n0 + row;
            if (gr < nrows) {
                int grow = (seg == 3) ? sBatch[row] : gr;
                v = *(const float4*)(base + (size_t)grow * 128 + cseg + slot * 4);
            }
            *(short4*)(&Abuf[row * 40 + slot * 4]) =
                make_short4(f2b(v.x), f2b(v.y), f2b(v.z), f2b(v.w));
        }
#pragma unroll
        for (int i = 0; i < 4; i++) {
            int idx = tid + i * 256;
            int c = idx >> 2, slot = idx & 3;
            uint4 v = *(const uint4*)(Wl1T + (size_t)(j0 + c) * 512 + k0 + slot * 8);
            *(uint4*)(&Bbuf[c * 40 + slot * 8]) = v;
        }
        __syncthreads();
        bf16x8 a[4], b[4];
#pragma unroll
        for (int fm = 0; fm < 4; fm++)
            a[fm] = *(const bf16x8*)(&Abuf[(fm * 16 + lr) * 40 + kg * 8]);
#pragma unroll
        for (int fn = 0; fn < 4; fn++)
            b[fn] = *(const bf16x8*)(&Bbuf[(wid * 64 + fn * 16 + lr) * 40 + kg * 8]);
#pragma unroll
        for (int fm = 0; fm < 4; fm++)
#pragma unroll
            for (int fn = 0; fn < 4; fn++)
                acc[fm][fn] = __builtin_amdgcn_mfma_f32_16x16x32_bf16(
                    a[fm], b[fn], acc[fm][fn], 0, 0, 0);
    }

#pragma unroll
    for (int fm = 0; fm < 4; fm++) {
#pragma unroll
        for (int r = 0; r < 4; r++) {
            float s = 0.f;
#pragma unroll
            for (int fn = 0; fn < 4; fn++) {
                float z = acc[fm][fn][r] + b1c[fn];
                z = z > 0.f ? z : 0.01f * z;
                s += z * w2[fn];
            }
            s += __shfl_xor(s, 1);
            s += __shfl_xor(s, 2);
            s += __shfl_xor(s, 4);
            s += __shfl_xor(s, 8);
            if (lr == 0) {
                int gr = n0 + fm * 16 + kg * 4 + r;
                if (gr < nrows) atomicAdd(out + gr, s);
            }
        }
    }
}

extern "C" void kernel_launch(void* const* d_in, const int* in_sizes, int n_in,
                              void* d_out, int out_size, void* d_ws, size_t ws_size,
                              hipStream_t stream) {
    const float* x     = (const float*)d_in[0];
    const int*   ei    = (const int*)d_in[1];
    const float* eattr = (const float*)d_in[2];
    const int*   batch = (const int*)d_in[3];
    const float* W[3]   = {(const float*)d_in[4],  (const float*)d_in[10], (const float*)d_in[16]};
    const float* We[3]  = {(const float*)d_in[5],  (const float*)d_in[11], (const float*)d_in[17]};
    const float* as_[3] = {(const float*)d_in[6],  (const float*)d_in[12], (const float*)d_in[18]};
    const float* ad_[3] = {(const float*)d_in[7],  (const float*)d_in[13], (const float*)d_in[19]};
    const float* ae_[3] = {(const float*)d_in[8],  (const float*)d_in[14], (const float*)d_in[20]};
    const float* b_[3]  = {(const float*)d_in[9],  (const float*)d_in[15], (const float*)d_in[21]};
    const float* Wl1 = (const float*)d_in[22];
    const float* bl1 = (const float*)d_in[23];
    const float* Wl2 = (const float*)d_in[24];
    const float* bl2 = (const float*)d_in[25];

    const int N = N_NODES, E = N_EDGES, G = N_GRAPH;

    float* ws    = (float*)d_ws;
    float* xs    = ws;                          // N*128 f32
    float* h0    = xs + (size_t)N * 128;
    float* h1b   = h0 + (size_t)N * 128;
    float* h2b   = h1b + (size_t)N * 128;
    float* hbuf[3] = {h0, h1b, h2b};
    float* alsrc = h2b + (size_t)N * 128;       // N*8
    float* aldst = alsrc + (size_t)N * 8;       // N*8
    float* pool  = aldst + (size_t)N * 8;       // G*128
    float* aeW   = pool + (size_t)G * 128;      // 128
    short* xsb   = (short*)(aeW + 128);         // N*128 bf16
    short* aleb  = xsb + (size_t)N * 128;       // E*8 bf16
    short* wl1t  = aleb + (size_t)E * 8;        // 512*512 bf16
    int*   cnt     = (int*)(wl1t + 512 * 512);  // N
    int*   rowptr  = cnt + N;                   // N+1
    int*   cursor  = rowptr + N + 1;            // N
    int*   part    = cursor + N;                // 256
    int*   pos     = part + 256;                // E
    int*   csr_src = pos + E;                   // E

    // ---- once per call: transpose Wl1, build dst-CSR ----
    wl1t_k<<<1024, 256, 0, stream>>>(Wl1, wl1t);
    hipMemsetAsync(cnt, 0, (size_t)N * sizeof(int), stream);
    hist_k<<<(E + 255) / 256, 256, 0, stream>>>(ei, cnt, E);
    const int nblk = (N + 255) / 256;   // 196
    scan1_k<<<nblk, 256, 0, stream>>>(cnt, rowptr, part, N);
    scan2_k<<<1, 256, 0, stream>>>(part, nblk);
    scan3_k<<<nblk, 256, 0, stream>>>(rowptr, part, cursor, N, E);
    scatter_k<<<(E + 255) / 256, 256, 0, stream>>>(ei, cursor, pos, csr_src, E);

    for (int l = 0; l < 3; l++) {
        const float* Ain = (l == 0) ? x : hbuf[l - 1];
        gemm128<<<(N + 63) / 64, 256, 0, stream>>>(Ain, W[l], xs, xsb, N);
        node_al<<<(N * 8 + 255) / 256, 256, 0, stream>>>(xs, as_[l], ad_[l], alsrc, aldst, N);
        aew_k<<<1, 128, 0, stream>>>(We[l], ae_[l], aeW);
        ale_k<<<(E + 255) / 256, 256, 0, stream>>>(ei, eattr, alsrc, aeW, pos, aleb, E);
        gather_k<<<(N + 3) / 4, 256, 0, stream>>>(rowptr, csr_src, aleb, aldst, xsb,
                                                  b_[l], hbuf[l], N);
    }
    hipMemsetAsync(pool, 0, (size_t)G * 128 * sizeof(float), stream);
    pool_k<<<(N * 128 + 255) / 256, 256, 0, stream>>>(hbuf[2], batch, pool, N);

    init_out<<<(N + 255) / 256, 256, 0, stream>>>((float*)d_out, bl2, N);
    dim3 fg((N + 63) / 64, 2);
    final_mfma<<<fg, 256, 0, stream>>>(hbuf[0], hbuf[1], hbuf[2], pool, batch,
                                       wl1t, bl1, Wl2, (float*)d_out, N);
}

// Round 6
// 528.001 us; speedup vs baseline: 1.2843x; 1.0874x over previous
//
#include <hip/hip_runtime.h>

#define N_NODES 50000
#define N_EDGES 800000
#define N_GRAPH 1000

typedef short bf16x8 __attribute__((ext_vector_type(8)));
typedef float f32x4 __attribute__((ext_vector_type(4)));

__device__ inline short f2b(float f) {   // f32 -> bf16 (RNE)
    union { float f; unsigned u; } x; x.f = f;
    unsigned r = x.u + 0x7FFF + ((x.u >> 16) & 1);
    return (short)(r >> 16);
}
__device__ inline float b2f_lo(unsigned v) {
    union { unsigned u; float f; } x; x.u = v << 16; return x.f;
}
__device__ inline float b2f_hi(unsigned v) {
    union { unsigned u; float f; } x; x.u = v & 0xFFFF0000u; return x.f;
}
__device__ inline float b2f_s(short s) {
    union { unsigned u; float f; } x; x.u = ((unsigned)(unsigned short)s) << 16; return x.f;
}
__device__ inline unsigned pack2(short lo, short hi) {
    return ((unsigned)(unsigned short)lo) | (((unsigned)(unsigned short)hi) << 16);
}

// ---------------- f32 -> bf16 bulk convert (vectorized) ----------------
__global__ void f2b_bulk(const float* __restrict__ in, short* __restrict__ out, int n4) {
    int t = blockIdx.x * blockDim.x + threadIdx.x;
    if (t >= n4) return;
    float4 v = *(const float4*)(in + (size_t)t * 4);
    *(short4*)(out + (size_t)t * 4) = make_short4(f2b(v.x), f2b(v.y), f2b(v.z), f2b(v.w));
}

// ---------------- W[128(k)][128(c)] f32 -> WbT[c][k] bf16 ----------------
__global__ void wbt_k(const float* __restrict__ W, short* __restrict__ WbT) {
    int idx = blockIdx.x * blockDim.x + threadIdx.x;   // 16384
    int k = idx >> 7, c = idx & 127;
    WbT[(size_t)c * 128 + k] = f2b(W[idx]);
}

// ---------------- layer GEMM via MFMA: Ab[N,128]bf16 @ W -> xs f32 + xsb bf16 ----------------
// BM=64 rows/block, BN=128 (all cols). 4 waves: wave = 32 rows x 64 cols.
// B-fragments straight from L2-resident WbT (32 KB). A staged [kslot][row][16B].
__global__ __launch_bounds__(256) void gemm_mfma(const short* __restrict__ Ab,
                                                 const short* __restrict__ WbT,
                                                 float* __restrict__ out,
                                                 short* __restrict__ outb, int nrows) {
    __shared__ short Abuf[4][64][8];   // 4 KB, [k-slot][row][8 bf16]
    const int tid = threadIdx.x;
    const int n0 = blockIdx.x * 64;
    const int wid = tid >> 6, lane = tid & 63;
    const int lr = lane & 15, kg = lane >> 4;
    const int wr = (wid >> 1) * 32;    // wave row offset (0/32)
    const int wc = (wid & 1) * 64;     // wave col offset (0/64)

    f32x4 acc[2][4] = {};

    for (int k0 = 0; k0 < 128; k0 += 32) {
        __syncthreads();
        {   // stage A: 64 rows x 32 k = 256 uint4, one per thread
            int row = tid >> 2, q = tid & 3;
            int gr = n0 + row;
            uint4 v = make_uint4(0, 0, 0, 0);
            if (gr < nrows) v = *(const uint4*)(Ab + (size_t)gr * 128 + k0 + q * 8);
            *(uint4*)(&Abuf[q][row][0]) = v;
        }
        __syncthreads();
        bf16x8 a[2], b[4];
#pragma unroll
        for (int fm = 0; fm < 2; fm++)
            a[fm] = *(const bf16x8*)(&Abuf[kg][wr + fm * 16 + lr][0]);
#pragma unroll
        for (int fn = 0; fn < 4; fn++)
            b[fn] = *(const bf16x8*)(WbT + (size_t)(wc + fn * 16 + lr) * 128 + k0 + kg * 8);
#pragma unroll
        for (int fm = 0; fm < 2; fm++)
#pragma unroll
            for (int fn = 0; fn < 4; fn++)
                acc[fm][fn] = __builtin_amdgcn_mfma_f32_16x16x32_bf16(
                    a[fm], b[fn], acc[fm][fn], 0, 0, 0);
    }
#pragma unroll
    for (int fm = 0; fm < 2; fm++) {
#pragma unroll
        for (int r = 0; r < 4; r++) {
            int gr = n0 + wr + fm * 16 + kg * 4 + r;
            if (gr < nrows) {
#pragma unroll
                for (int fn = 0; fn < 4; fn++) {
                    int col = wc + fn * 16 + lr;
                    float z = acc[fm][fn][r];
                    out[(size_t)gr * 128 + col] = z;
                    outb[(size_t)gr * 128 + col] = f2b(z);
                }
            }
        }
    }
}

// ---------------- per-node attention coefficients ----------------
__global__ void node_al(const float* __restrict__ xs, const float* __restrict__ a_s,
                        const float* __restrict__ a_d, float* __restrict__ alsrc,
                        float* __restrict__ aldst, int n) {
    int t = blockIdx.x * blockDim.x + threadIdx.x;
    if (t >= n * 8) return;
    int node = t >> 3, h = t & 7;
    const float4* xp = (const float4*)(xs + (size_t)node * 128 + h * 16);
    const float4* sp = (const float4*)(a_s + h * 16);
    const float4* dp = (const float4*)(a_d + h * 16);
    float ss = 0.f, dd = 0.f;
#pragma unroll
    for (int q = 0; q < 4; q++) {
        float4 x4 = xp[q], s4 = sp[q], d4 = dp[q];
        ss += x4.x * s4.x + x4.y * s4.y + x4.z * s4.z + x4.w * s4.w;
        dd += x4.x * d4.x + x4.y * d4.y + x4.z * d4.z + x4.w * d4.w;
    }
    alsrc[t] = ss;
    aldst[t] = dd;
}

// ---------------- aeW[k][h] = sum_c We[k, h*16+c] * ae[h,c] ----------------
__global__ void aew_k(const float* __restrict__ We, const float* __restrict__ ae,
                      float* __restrict__ aeW) {
    int t = threadIdx.x;   // 128 threads
    int k = t >> 3, h = t & 7;
    float s = 0.f;
#pragma unroll
    for (int c = 0; c < 16; c++) s += We[k * 128 + h * 16 + c] * ae[h * 16 + c];
    aeW[k * 8 + h] = s;
}

// ---------------- CSR build ----------------
__global__ void hist_k(const int* __restrict__ ei, int* __restrict__ cnt, int ne) {
    int e = blockIdx.x * blockDim.x + threadIdx.x;
    if (e < ne) atomicAdd(&cnt[ei[ne + e]], 1);
}

__global__ void scan1_k(const int* __restrict__ cnt, int* __restrict__ rowptr,
                        int* __restrict__ part, int n) {
    __shared__ int s[256];
    int tid = threadIdx.x;
    int i = blockIdx.x * 256 + tid;
    int v = (i < n) ? cnt[i] : 0;
    s[tid] = v; __syncthreads();
#pragma unroll
    for (int off = 1; off < 256; off <<= 1) {
        int t = (tid >= off) ? s[tid - off] : 0;
        __syncthreads();
        s[tid] += t;
        __syncthreads();
    }
    if (i < n) rowptr[i] = s[tid] - v;
    if (tid == 255) part[blockIdx.x] = s[255];
}

__global__ void scan2_k(int* __restrict__ part, int npart) {
    __shared__ int s[256];
    int tid = threadIdx.x;
    int v = (tid < npart) ? part[tid] : 0;
    s[tid] = v; __syncthreads();
#pragma unroll
    for (int off = 1; off < 256; off <<= 1) {
        int t = (tid >= off) ? s[tid - off] : 0;
        __syncthreads();
        s[tid] += t;
        __syncthreads();
    }
    if (tid < npart) part[tid] = s[tid] - v;
}

__global__ void scan3_k(int* __restrict__ rowptr, const int* __restrict__ part,
                        int* __restrict__ cursor, int n, int ne) {
    int i = blockIdx.x * 256 + threadIdx.x;
    if (i < n) {
        int r = rowptr[i] + part[blockIdx.x];
        rowptr[i] = r;
        cursor[i] = r;
    }
    if (i == 0) rowptr[n] = ne;
}

__global__ void scatter_k(const int* __restrict__ ei, int* __restrict__ cursor,
                          int* __restrict__ pos, int* __restrict__ csr_src, int ne) {
    int e = blockIdx.x * blockDim.x + threadIdx.x;
    if (e >= ne) return;
    int d = ei[ne + e];
    int p = atomicAdd(&cursor[d], 1);
    pos[e] = p;
    csr_src[p] = ei[e];
}

// ---------------- per-edge logits (alsrc + al_e), bf16, CSR order ----------------
__global__ __launch_bounds__(256) void ale_k(const int* __restrict__ ei,
                                             const float* __restrict__ eattr,
                                             const float* __restrict__ alsrc,
                                             const float* __restrict__ aeW,
                                             const int* __restrict__ pos,
                                             short* __restrict__ aleb, int ne) {
    __shared__ float sAe[128];
    if (threadIdx.x < 128) sAe[threadIdx.x] = aeW[threadIdx.x];
    __syncthreads();
    int e = blockIdx.x * blockDim.x + threadIdx.x;
    if (e >= ne) return;
    float ea[16];
    const float4* ep = (const float4*)(eattr + (size_t)e * 16);
#pragma unroll
    for (int q = 0; q < 4; q++) {
        float4 v = ep[q];
        ea[q * 4 + 0] = v.x; ea[q * 4 + 1] = v.y; ea[q * 4 + 2] = v.z; ea[q * 4 + 3] = v.w;
    }
    int s = ei[e];
    float out[8];
#pragma unroll
    for (int h = 0; h < 8; h++) out[h] = alsrc[s * 8 + h];
#pragma unroll
    for (int k = 0; k < 16; k++)
#pragma unroll
        for (int h = 0; h < 8; h++) out[h] += ea[k] * sAe[k * 8 + h];
    short v8[8];
#pragma unroll
    for (int h = 0; h < 8; h++) v8[h] = f2b(out[h]);
    short* op = aleb + (size_t)pos[e] * 8;
    *(short4*)(op)     = make_short4(v8[0], v8[1], v8[2], v8[3]);
    *(short4*)(op + 4) = make_short4(v8[4], v8[5], v8[6], v8[7]);
}

// ---------------- gather: one wave per dst; shuffle-free; writes bf16 h ----------------
__global__ __launch_bounds__(256) void gather_k(const int* __restrict__ rowptr,
                                                const int* __restrict__ csr_src,
                                                const short* __restrict__ aleb,
                                                const float* __restrict__ aldst,
                                                const short* __restrict__ xsb,
                                                const float* __restrict__ b,
                                                short* __restrict__ houtb, int n) {
    int dst = blockIdx.x * 4 + (threadIdx.x >> 6);
    if (dst >= n) return;
    const int lane = threadIdx.x & 63;
    const int h = lane >> 3;
    const float L2E = 1.44269504f;
    int p0 = rowptr[dst], p1 = rowptr[dst + 1];
    float ald = aldst[dst * 8 + h];
    float den = 0.f, acc0 = 0.f, acc1 = 0.f;
    int p = p0;
    for (; p + 1 < p1; p += 2) {
        int s0 = csr_src[p];
        int s1 = csr_src[p + 1];
        float al0 = b2f_s(aleb[(size_t)p * 8 + h]);
        float al1 = b2f_s(aleb[(size_t)(p + 1) * 8 + h]);
        unsigned v0 = *(const unsigned*)(xsb + (size_t)s0 * 128 + lane * 2);
        unsigned v1 = *(const unsigned*)(xsb + (size_t)s1 * 128 + lane * 2);
        float lg0 = al0 + ald; lg0 = lg0 > 0.f ? lg0 : 0.2f * lg0;
        float lg1 = al1 + ald; lg1 = lg1 > 0.f ? lg1 : 0.2f * lg1;
        float ex0 = exp2f(lg0 * L2E);
        float ex1 = exp2f(lg1 * L2E);
        den  += ex0 + ex1;
        acc0 += b2f_lo(v0) * ex0 + b2f_lo(v1) * ex1;
        acc1 += b2f_hi(v0) * ex0 + b2f_hi(v1) * ex1;
    }
    if (p < p1) {
        int s0 = csr_src[p];
        float al0 = b2f_s(aleb[(size_t)p * 8 + h]);
        unsigned v0 = *(const unsigned*)(xsb + (size_t)s0 * 128 + lane * 2);
        float lg0 = al0 + ald; lg0 = lg0 > 0.f ? lg0 : 0.2f * lg0;
        float ex0 = exp2f(lg0 * L2E);
        den  += ex0;
        acc0 += b2f_lo(v0) * ex0;
        acc1 += b2f_hi(v0) * ex0;
    }
    float inv = 1.f / (den + 1e-16f);
    const float2 bb = *(const float2*)(b + lane * 2);
    unsigned o = pack2(f2b(acc0 * inv + bb.x), f2b(acc1 * inv + bb.y));
    *(unsigned*)(houtb + (size_t)dst * 128 + lane * 2) = o;
}

// ---------------- global add pool (bf16 input, f32 atomics) ----------------
__global__ void pool_k(const short* __restrict__ h3b, const int* __restrict__ batch,
                       float* __restrict__ pool, int n) {
    int t = blockIdx.x * blockDim.x + threadIdx.x;
    if (t >= n * 128) return;
    int node = t >> 7, j = t & 127;
    atomicAdd(pool + (size_t)batch[node] * 128 + j, b2f_s(h3b[t]));
}

// ---------------- Wl1 [512(k),512(c)] f32 -> Wl1T [c][k] bf16 ----------------
__global__ void wl1t_k(const float* __restrict__ Wl1, short* __restrict__ Wl1T) {
    int idx = blockIdx.x * blockDim.x + threadIdx.x;   // 262144
    int k = idx >> 9, c = idx & 511;
    Wl1T[(size_t)c * 512 + k] = f2b(Wl1[idx]);
}

__global__ void init_out(float* __restrict__ out, const float* __restrict__ bl2, int n) {
    int t = blockIdx.x * blockDim.x + threadIdx.x;
    if (t < n) out[t] = bl2[0];
}

// ---------------- fused final MLP via bf16 MFMA (all-bf16 A, B from L2) ----------------
// BM=64, BN=256 (grid.y=2). 4 waves, each 64 rows x 64 cols.
__global__ __launch_bounds__(256) void final_mfma(
    const short* __restrict__ h1, const short* __restrict__ h2,
    const short* __restrict__ h3, const short* __restrict__ poolb,
    const int* __restrict__ batch, const short* __restrict__ Wl1T,
    const float* __restrict__ bl1, const float* __restrict__ Wl2,
    float* __restrict__ out, int nrows)
{
    __shared__ short Abuf[4][64][8];   // 4 KB, [k-slot][row][8 bf16]
    __shared__ int   sBatch[64];
    const int tid = threadIdx.x;
    const int n0 = blockIdx.x * 64;
    const int j0 = blockIdx.y * 256;
    const int wid = tid >> 6, lane = tid & 63;
    const int lr = lane & 15, kg = lane >> 4;

    if (tid < 64) {
        int gr = n0 + tid;
        sBatch[tid] = (gr < nrows) ? batch[gr] : 0;
    }
    float w2[4], b1c[4];
#pragma unroll
    for (int fn = 0; fn < 4; fn++) {
        int c = j0 + wid * 64 + fn * 16 + lr;
        w2[fn]  = Wl2[c];
        b1c[fn] = bl1[c];
    }

    f32x4 acc[4][4] = {};

    const int srow = tid >> 2, sq = tid & 3;   // staging indices
    for (int k0 = 0; k0 < 512; k0 += 32) {
        const int seg = k0 >> 7;
        const short* base = (seg == 0) ? h1 : (seg == 1) ? h2 : (seg == 2) ? h3 : poolb;
        const int cseg = k0 & 127;
        __syncthreads();   // also covers sBatch on first iter
        {   // stage A: 64 rows x 32 k = 256 uint4, one per thread
            uint4 v = make_uint4(0, 0, 0, 0);
            int gr = n0 + srow;
            if (gr < nrows) {
                int grow = (seg == 3) ? sBatch[srow] : gr;
                v = *(const uint4*)(base + (size_t)grow * 128 + cseg + sq * 8);
            }
            *(uint4*)(&Abuf[sq][srow][0]) = v;
        }
        __syncthreads();
        bf16x8 a[4], b[4];
#pragma unroll
        for (int fm = 0; fm < 4; fm++)
            a[fm] = *(const bf16x8*)(&Abuf[kg][fm * 16 + lr][0]);
#pragma unroll
        for (int fn = 0; fn < 4; fn++)
            b[fn] = *(const bf16x8*)(Wl1T + (size_t)(j0 + wid * 64 + fn * 16 + lr) * 512
                                     + k0 + kg * 8);
#pragma unroll
        for (int fm = 0; fm < 4; fm++)
#pragma unroll
            for (int fn = 0; fn < 4; fn++)
                acc[fm][fn] = __builtin_amdgcn_mfma_f32_16x16x32_bf16(
                    a[fm], b[fn], acc[fm][fn], 0, 0, 0);
    }

#pragma unroll
    for (int fm = 0; fm < 4; fm++) {
#pragma unroll
        for (int r = 0; r < 4; r++) {
            float s = 0.f;
#pragma unroll
            for (int fn = 0; fn < 4; fn++) {
                float z = acc[fm][fn][r] + b1c[fn];
                z = z > 0.f ? z : 0.01f * z;
                s += z * w2[fn];
            }
            s += __shfl_xor(s, 1);
            s += __shfl_xor(s, 2);
            s += __shfl_xor(s, 4);
            s += __shfl_xor(s, 8);
            if (lr == 0) {
                int gr = n0 + fm * 16 + kg * 4 + r;
                if (gr < nrows) atomicAdd(out + gr, s);
            }
        }
    }
}

extern "C" void kernel_launch(void* const* d_in, const int* in_sizes, int n_in,
                              void* d_out, int out_size, void* d_ws, size_t ws_size,
                              hipStream_t stream) {
    const float* x     = (const float*)d_in[0];
    const int*   ei    = (const int*)d_in[1];
    const float* eattr = (const float*)d_in[2];
    const int*   batch = (const int*)d_in[3];
    const float* W[3]   = {(const float*)d_in[4],  (const float*)d_in[10], (const float*)d_in[16]};
    const float* We[3]  = {(const float*)d_in[5],  (const float*)d_in[11], (const float*)d_in[17]};
    const float* as_[3] = {(const float*)d_in[6],  (const float*)d_in[12], (const float*)d_in[18]};
    const float* ad_[3] = {(const float*)d_in[7],  (const float*)d_in[13], (const float*)d_in[19]};
    const float* ae_[3] = {(const float*)d_in[8],  (const float*)d_in[14], (const float*)d_in[20]};
    const float* b_[3]  = {(const float*)d_in[9],  (const float*)d_in[15], (const float*)d_in[21]};
    const float* Wl1 = (const float*)d_in[22];
    const float* bl1 = (const float*)d_in[23];
    const float* Wl2 = (const float*)d_in[24];
    const float* bl2 = (const float*)d_in[25];

    const int N = N_NODES, E = N_EDGES, G = N_GRAPH;

    float* ws    = (float*)d_ws;
    float* xs    = ws;                          // N*128 f32
    float* alsrc = xs + (size_t)N * 128;        // N*8
    float* aldst = alsrc + (size_t)N * 8;       // N*8
    float* pool  = aldst + (size_t)N * 8;       // G*128
    float* aeW   = pool + (size_t)G * 128;      // 128
    short* xb    = (short*)(aeW + 128);         // N*128 bf16 (input x)
    short* xsb   = xb + (size_t)N * 128;        // N*128 bf16 (layer GEMM out)
    short* hb0   = xsb + (size_t)N * 128;       // N*128 bf16
    short* hb1   = hb0 + (size_t)N * 128;
    short* hb2   = hb1 + (size_t)N * 128;
    short* hb[3] = {hb0, hb1, hb2};
    short* poolb = hb2 + (size_t)N * 128;       // G*128 bf16
    short* wbt0  = poolb + (size_t)G * 128;     // 3 x 128*128 bf16
    short* wbt1  = wbt0 + 16384;
    short* wbt2  = wbt1 + 16384;
    short* wbt[3] = {wbt0, wbt1, wbt2};
    short* wl1t  = wbt2 + 16384;                // 512*512 bf16
    short* aleb  = wl1t + 262144;               // E*8 bf16
    int*   cnt     = (int*)(aleb + (size_t)E * 8);  // N
    int*   rowptr  = cnt + N;                   // N+1
    int*   cursor  = rowptr + N + 1;            // N
    int*   part    = cursor + N;                // 256
    int*   pos     = part + 256;                // E
    int*   csr_src = pos + E;                   // E

    // ---- once per call: bf16 conversions + dst-CSR ----
    f2b_bulk<<<(N * 32 + 255) / 256, 256, 0, stream>>>(x, xb, N * 32);
    for (int l = 0; l < 3; l++)
        wbt_k<<<64, 256, 0, stream>>>(W[l], wbt[l]);
    wl1t_k<<<1024, 256, 0, stream>>>(Wl1, wl1t);
    hipMemsetAsync(cnt, 0, (size_t)N * sizeof(int), stream);
    hist_k<<<(E + 255) / 256, 256, 0, stream>>>(ei, cnt, E);
    const int nblk = (N + 255) / 256;   // 196
    scan1_k<<<nblk, 256, 0, stream>>>(cnt, rowptr, part, N);
    scan2_k<<<1, 256, 0, stream>>>(part, nblk);
    scan3_k<<<nblk, 256, 0, stream>>>(rowptr, part, cursor, N, E);
    scatter_k<<<(E + 255) / 256, 256, 0, stream>>>(ei, cursor, pos, csr_src, E);

    for (int l = 0; l < 3; l++) {
        const short* Ain = (l == 0) ? xb : hb[l - 1];
        gemm_mfma<<<(N + 63) / 64, 256, 0, stream>>>(Ain, wbt[l], xs, xsb, N);
        node_al<<<(N * 8 + 255) / 256, 256, 0, stream>>>(xs, as_[l], ad_[l], alsrc, aldst, N);
        aew_k<<<1, 128, 0, stream>>>(We[l], ae_[l], aeW);
        ale_k<<<(E + 255) / 256, 256, 0, stream>>>(ei, eattr, alsrc, aeW, pos, aleb, E);
        gather_k<<<(N + 3) / 4, 256, 0, stream>>>(rowptr, csr_src, aleb, aldst, xsb,
                                                  b_[l], hb[l], N);
    }
    hipMemsetAsync(pool, 0, (size_t)G * 128 * sizeof(float), stream);
    pool_k<<<(N * 128 + 255) / 256, 256, 0, stream>>>(hb[2], batch, pool, N);
    f2b_bulk<<<(G * 32 + 255) / 256, 256, 0, stream>>>(pool, poolb, G * 32);

    init_out<<<(N + 255) / 256, 256, 0, stream>>>((float*)d_out, bl2, N);
    dim3 fg((N + 63) / 64, 2);
    final_mfma<<<fg, 256, 0, stream>>>(hb[0], hb[1], hb[2], poolb, batch,
                                       wl1t, bl1, Wl2, (float*)d_out, N);
}